// Round 1
// baseline (6088.375 us; speedup 1.0000x reference)
//
#include <hip/hip_runtime.h>

// Problem constants
#define BB 64
#define TT 12
#define NN 1000
#define HH 64
#define MM 4
#define NP 1024          // padded node dim
#define FP0 96           // padded layer-0 feature (real 65)
#define FP1 128          // layer-1 feature (64+64)
#define NC0 (BB*FP0)     // 6144
#define NC1 (BB*FP1)     // 8192
#define RROWS (NN*BB)    // 64000 valid (k,b) rows

typedef __bf16 bf16x8 __attribute__((ext_vector_type(8)));
typedef float f32x4 __attribute__((ext_vector_type(4)));

__device__ __forceinline__ unsigned short f2b(float f) {
  union { float f; unsigned u; } x; x.f = f;
  unsigned u = x.u;
  u += 0x7FFFu + ((u >> 16) & 1u);   // round-to-nearest-even
  return (unsigned short)(u >> 16);
}

__device__ __forceinline__ void gload16(const void* g, void* l) {
  __builtin_amdgcn_global_load_lds((const __attribute__((address_space(1))) void*)g,
                                   (__attribute__((address_space(3))) void*)l, 16, 0, 0);
}

// ---------------- setup kernels ----------------

// supports [4][1000][1000] f32 -> Sb [4][1024][1024] bf16, zero padded
__global__ void prep_s_k(const float* __restrict__ S, unsigned short* __restrict__ Sb) {
  long idx = (long)blockIdx.x * 256 + threadIdx.x;   // 4*1024*1024
  if (idx >= 4194304L) return;
  int j = (int)(idx >> 20);
  int r = (int)((idx >> 10) & 1023);
  int c = (int)(idx & 1023);
  float v = (r < NN && c < NN) ? S[((long)j * NN + r) * NN + c] : 0.f;
  Sb[idx] = f2b(v);
}

// WT[o][j*Fpad + l] bf16 (o<128): o<64 from wA, o>=64 from wB (or zero)
__global__ void prep_wt_k(const float* __restrict__ wA, const float* __restrict__ wB,
                          unsigned short* __restrict__ WT, int F, int Fpad) {
  int Kt = 4 * Fpad;
  int idx = blockIdx.x * 256 + threadIdx.x;
  if (idx >= 128 * Kt) return;
  int o = idx / Kt, kk = idx % Kt;
  int j = kk / Fpad, l = kk % Fpad;
  float v = 0.f;
  if (l < F) {
    if (o < 64) v = wA ? wA[((long)j * F + l) * 64 + o] : 0.f;
    else        v = wB ? wB[((long)j * F + l) * 64 + (o - 64)] : 0.f;
  }
  WT[idx] = f2b(v);
}

// init_hidden [2][B][N][H] -> H0/H1 [r=(n*64+b)][64] f32
__global__ void init_h_k(const float* __restrict__ ih, float* __restrict__ H0,
                         float* __restrict__ H1) {
  long idx = (long)blockIdx.x * 256 + threadIdx.x;   // 64*1000*64
  if (idx >= 4096000L) return;
  int b = (int)(idx / 64000);
  long rem = idx % 64000;
  int n = (int)(rem / 64), o = (int)(rem % 64);
  long dst = ((long)n * 64 + b) * 64 + o;
  H0[dst] = ih[(long)b * 64000 + rem];
  H1[dst] = ih[4096000L + (long)b * 64000 + rem];
}

// ---------------- build (transpose) kernels ----------------
// XT[(b*Fpad + l)][m] bf16, m in [0,1024)

__global__ void build_xs0_k(const float* __restrict__ inp, const float* __restrict__ H0,
                            unsigned short* __restrict__ XT, int t) {
  __shared__ float tile[128][65];
  int m0 = blockIdx.x * 128, b = blockIdx.y, tid = threadIdx.x;
  for (int q = 0; q < 32; ++q) {
    int mm = q * 4 + (tid >> 6), o = tid & 63;
    int m = m0 + mm;
    tile[mm][o] = (m < NN) ? H0[((long)m * 64 + b) * 64 + o] : 0.f;
  }
  __syncthreads();
  for (int q = 0; q < 48; ++q) {               // 96 l-rows * 128 m / 256
    int idx = q * 256 + tid;
    int l = idx >> 7, mm = idx & 127, m = m0 + mm;
    float v;
    if (l == 0)       v = (m < NN) ? inp[((long)b * TT + t) * NN + m] : 0.f;
    else if (l <= 64) v = tile[mm][l - 1];
    else              v = 0.f;
    XT[((long)(b * FP0 + l)) * NP + m] = f2b(v);
  }
}

__global__ void build_xc0_k(const float* __restrict__ inp, const float* __restrict__ H0,
                            const float* __restrict__ RU, unsigned short* __restrict__ XT,
                            int t) {
  __shared__ float tile[128][65];
  int m0 = blockIdx.x * 128, b = blockIdx.y, tid = threadIdx.x;
  for (int q = 0; q < 32; ++q) {
    int mm = q * 4 + (tid >> 6), o = tid & 63;
    int m = m0 + mm;
    float v = 0.f;
    if (m < NN) {
      long r = (long)m * 64 + b;
      v = RU[r * 128 + o] * H0[r * 64 + o];    // r-gate * h
    }
    tile[mm][o] = v;
  }
  __syncthreads();
  for (int q = 0; q < 48; ++q) {
    int idx = q * 256 + tid;
    int l = idx >> 7, mm = idx & 127, m = m0 + mm;
    float v;
    if (l == 0)       v = (m < NN) ? inp[((long)b * TT + t) * NN + m] : 0.f;
    else if (l <= 64) v = tile[mm][l - 1];
    else              v = 0.f;
    XT[((long)(b * FP0 + l)) * NP + m] = f2b(v);
  }
}

__global__ void build_xs1_k(const float* __restrict__ H0, const float* __restrict__ H1,
                            unsigned short* __restrict__ XT) {
  __shared__ float tile[128][65];
  int m0 = blockIdx.x * 128, b = blockIdx.y, tid = threadIdx.x;
  // phase A: l 0..63 <- H0 (cell input)
  for (int q = 0; q < 32; ++q) {
    int mm = q * 4 + (tid >> 6), o = tid & 63;
    int m = m0 + mm;
    tile[mm][o] = (m < NN) ? H0[((long)m * 64 + b) * 64 + o] : 0.f;
  }
  __syncthreads();
  for (int q = 0; q < 32; ++q) {
    int idx = q * 256 + tid;
    int l = idx >> 7, mm = idx & 127;
    XT[((long)(b * FP1 + l)) * NP + m0 + mm] = f2b(tile[mm][l]);
  }
  __syncthreads();
  // phase B: l 64..127 <- H1 (state)
  for (int q = 0; q < 32; ++q) {
    int mm = q * 4 + (tid >> 6), o = tid & 63;
    int m = m0 + mm;
    tile[mm][o] = (m < NN) ? H1[((long)m * 64 + b) * 64 + o] : 0.f;
  }
  __syncthreads();
  for (int q = 0; q < 32; ++q) {
    int idx = q * 256 + tid;
    int l = idx >> 7, mm = idx & 127;
    XT[((long)(b * FP1 + 64 + l)) * NP + m0 + mm] = f2b(tile[mm][l]);
  }
}

__global__ void build_xc1_k(const float* __restrict__ H0, const float* __restrict__ H1,
                            const float* __restrict__ RU, unsigned short* __restrict__ XT) {
  __shared__ float tile[128][65];
  int m0 = blockIdx.x * 128, b = blockIdx.y, tid = threadIdx.x;
  for (int q = 0; q < 32; ++q) {
    int mm = q * 4 + (tid >> 6), o = tid & 63;
    int m = m0 + mm;
    tile[mm][o] = (m < NN) ? H0[((long)m * 64 + b) * 64 + o] : 0.f;
  }
  __syncthreads();
  for (int q = 0; q < 32; ++q) {
    int idx = q * 256 + tid;
    int l = idx >> 7, mm = idx & 127;
    XT[((long)(b * FP1 + l)) * NP + m0 + mm] = f2b(tile[mm][l]);
  }
  __syncthreads();
  for (int q = 0; q < 32; ++q) {
    int mm = q * 4 + (tid >> 6), o = tid & 63;
    int m = m0 + mm;
    float v = 0.f;
    if (m < NN) {
      long r = (long)m * 64 + b;
      v = RU[r * 128 + o] * H1[r * 64 + o];    // r1-gate * h1
    }
    tile[mm][o] = v;
  }
  __syncthreads();
  for (int q = 0; q < 32; ++q) {
    int idx = q * 256 + tid;
    int l = idx >> 7, mm = idx & 127;
    XT[((long)(b * FP1 + 64 + l)) * NP + m0 + mm] = f2b(tile[mm][l]);
  }
}

// ---------------- unified MFMA GEMM ----------------
// C[M][*] = A[M][K] * BT[*][K]^T ; both operands row-major, K contiguous.
// 128x128 tile, BK=32, 4 waves, global_load_lds staging.
// EPI 0: bf16 store to C (ldc cols), + blockIdx.z * czstr (A += z*azstr too)
// EPI 1: fp32 sigmoid(acc + bias) -> RU[r*128 + c]; p0=bias_r, p1=bias_u
// EPI 2: c<64: t=tanh(acc+p0[c]); u=p1[r*128+64+c]; H[r*64+c]=u*h+(1-u)*t
template <int EPI>
__global__ __launch_bounds__(256)
void gemm_k(const unsigned short* __restrict__ A, long azstr, int lda, int acs, long ajstr,
            const unsigned short* __restrict__ BT, int ldb, int ksteps,
            void* __restrict__ Cv, long czstr, int ldc,
            const float* __restrict__ p0, const float* __restrict__ p1) {
  __shared__ unsigned short As[4096];
  __shared__ unsigned short Bs[4096];
  const int tid = threadIdx.x;
  const int lane = tid & 63;
  const int w = tid >> 6;
  const int wr = (w >> 1) * 64, wc = (w & 1) * 64;
  const long m0 = (long)blockIdx.x * 128;
  const long n0 = (long)blockIdx.y * 128;
  A += (long)blockIdx.z * azstr;

  const int rl = lane & 15;
  const int kb = (lane >> 4) * 8;
  const int s_r = tid >> 2;            // staging row 0..63
  const int s_k = (tid & 3) * 8;       // staging k-offset

  f32x4 acc[4][4];
  for (int i = 0; i < 4; ++i)
    for (int j = 0; j < 4; ++j)
      acc[i][j] = (f32x4){0.f, 0.f, 0.f, 0.f};

  int jc = 0, lc = 0;
  for (int kt = 0; kt < ksteps; ++kt) {
    const unsigned short* Astep = A + (long)jc * ajstr + (long)lc * 32;
    const unsigned short* Bstep = BT + (long)kt * 32;
    gload16(Astep + (m0 + s_r) * (long)lda + s_k,       &As[tid * 8]);
    gload16(Astep + (m0 + 64 + s_r) * (long)lda + s_k,  &As[2048 + tid * 8]);
    gload16(Bstep + (n0 + s_r) * (long)ldb + s_k,       &Bs[tid * 8]);
    gload16(Bstep + (n0 + 64 + s_r) * (long)ldb + s_k,  &Bs[2048 + tid * 8]);
    __syncthreads();
    bf16x8 af[4], bg[4];
#pragma unroll
    for (int i = 0; i < 4; ++i) {
      af[i] = *(const bf16x8*)((const void*)&As[(wr + i * 16 + rl) * 32 + kb]);
      bg[i] = *(const bf16x8*)((const void*)&Bs[(wc + i * 16 + rl) * 32 + kb]);
    }
#pragma unroll
    for (int mi = 0; mi < 4; ++mi)
#pragma unroll
      for (int ni = 0; ni < 4; ++ni)
        acc[mi][ni] = __builtin_amdgcn_mfma_f32_16x16x32_bf16(af[mi], bg[ni], acc[mi][ni], 0, 0, 0);
    __syncthreads();
    if (++lc == acs) { lc = 0; ++jc; }
  }

  const int rb = (lane >> 4) * 4;      // C/D: row=(lane>>4)*4+reg, col=lane&15
  const int cl = lane & 15;
  if constexpr (EPI == 0) {
    unsigned short* C = (unsigned short*)Cv + (long)blockIdx.z * czstr;
#pragma unroll
    for (int mi = 0; mi < 4; ++mi) {
      long r = m0 + wr + mi * 16 + rb;
#pragma unroll
      for (int ni = 0; ni < 4; ++ni) {
        long c = n0 + wc + ni * 16 + cl;
#pragma unroll
        for (int jj = 0; jj < 4; ++jj)
          C[(r + jj) * (long)ldc + c] = f2b(acc[mi][ni][jj]);
      }
    }
  } else if constexpr (EPI == 1) {
    float* RUo = (float*)Cv;
#pragma unroll
    for (int mi = 0; mi < 4; ++mi) {
      long r = m0 + wr + mi * 16 + rb;
#pragma unroll
      for (int ni = 0; ni < 4; ++ni) {
        int c = (int)(n0 + wc + ni * 16 + cl);
        float bias = (c < 64) ? p0[c] : p1[c - 64];
#pragma unroll
        for (int jj = 0; jj < 4; ++jj) {
          float v = acc[mi][ni][jj] + bias;
          RUo[(r + jj) * 128 + c] = 1.f / (1.f + __expf(-v));
        }
      }
    }
  } else {
    float* H = (float*)Cv;
#pragma unroll
    for (int mi = 0; mi < 4; ++mi) {
      long r = m0 + wr + mi * 16 + rb;
#pragma unroll
      for (int ni = 0; ni < 4; ++ni) {
        int c = (int)(n0 + wc + ni * 16 + cl);
        if (c < 64) {
#pragma unroll
          for (int jj = 0; jj < 4; ++jj) {
            float cv = tanhf(acc[mi][ni][jj] + p0[c]);
            float u = p1[(r + jj) * 128 + 64 + c];
            float h = H[(r + jj) * 64 + c];
            H[(r + jj) * 64 + c] = u * h + (1.f - u) * cv;
          }
        }
      }
    }
  }
}

// ---------------- projection ----------------
__global__ void proj_k(const float* __restrict__ H1, const float* __restrict__ pw,
                       const float* __restrict__ pb, float* __restrict__ out, int t) {
  int idx = blockIdx.x * 256 + threadIdx.x;   // r = n*64 + b, 64000
  if (idx >= RROWS) return;
  int n = idx >> 6, b = idx & 63;
  const float* h = H1 + (long)idx * 64;
  float s = pb[0];
#pragma unroll
  for (int o = 0; o < 64; ++o) s += h[o] * pw[o];
  out[((long)b * (TT - 1) + t) * NN + n] = s;
}

// ---------------- launcher ----------------
extern "C" void kernel_launch(void* const* d_in, const int* in_sizes, int n_in,
                              void* d_out, int out_size, void* d_ws, size_t ws_size,
                              hipStream_t stream) {
  const float* inp = (const float*)d_in[0];
  const float* ih  = (const float*)d_in[1];
  const float* sup = (const float*)d_in[2];
  // d_in[3] = teacher_force_ratio (==1, ignored)
  const float* w0r = (const float*)d_in[4];
  const float* b0r = (const float*)d_in[5];
  const float* w0u = (const float*)d_in[6];
  const float* b0u = (const float*)d_in[7];
  const float* w0c = (const float*)d_in[8];
  const float* b0c = (const float*)d_in[9];
  const float* w1r = (const float*)d_in[10];
  const float* b1r = (const float*)d_in[11];
  const float* w1u = (const float*)d_in[12];
  const float* b1u = (const float*)d_in[13];
  const float* w1c = (const float*)d_in[14];
  const float* b1c = (const float*)d_in[15];
  const float* pw  = (const float*)d_in[16];
  const float* pb  = (const float*)d_in[17];
  float* out = (float*)d_out;

  char* ws = (char*)d_ws;
  unsigned short* Sb   = (unsigned short*)(ws + 0);          //  8,388,608
  unsigned short* XT   = (unsigned short*)(ws + 8388608);    // 16,777,216
  unsigned short* AG   = (unsigned short*)(ws + 25165824);   // 67,108,864
  float* RU            = (float*)(ws + 92274688);            // 32,768,000
  float* H0            = (float*)(ws + 125042688);           // 16,384,000
  float* H1            = (float*)(ws + 141426688);           // 16,384,000
  unsigned short* Wru0 = (unsigned short*)(ws + 157810688);  //     98,304
  unsigned short* Wc0  = (unsigned short*)(ws + 157908992);  //     98,304
  unsigned short* Wru1 = (unsigned short*)(ws + 158007296);  //    131,072
  unsigned short* Wc1  = (unsigned short*)(ws + 158138368);  //    131,072

  const long JS0 = 1024L * 64 * FP0;   // aggr j-stride, layer0
  const long JS1 = 1024L * 64 * FP1;   // layer1

  prep_s_k<<<16384, 256, 0, stream>>>(sup, Sb);
  prep_wt_k<<<192, 256, 0, stream>>>(w0r, w0u, Wru0, 65, FP0);
  prep_wt_k<<<192, 256, 0, stream>>>(w0c, nullptr, Wc0, 65, FP0);
  prep_wt_k<<<256, 256, 0, stream>>>(w1r, w1u, Wru1, 128, FP1);
  prep_wt_k<<<256, 256, 0, stream>>>(w1c, nullptr, Wc1, 128, FP1);
  init_h_k<<<16000, 256, 0, stream>>>(ih, H0, H1);

  for (int t = 0; t < TT - 1; ++t) {
    // ---- layer 0 ----
    build_xs0_k<<<dim3(8, 64), 256, 0, stream>>>(inp, H0, XT, t);
    gemm_k<0><<<dim3(8, NC0 / 128, 4), 256, 0, stream>>>(
        Sb, 1024L * 1024, 1024, 32, 0, XT, 1024, 32, AG, 1024L * NC0, NC0, nullptr, nullptr);
    gemm_k<1><<<dim3(500, 1, 1), 256, 0, stream>>>(
        AG, 0, FP0, FP0 / 32, JS0, Wru0, 4 * FP0, 12, RU, 0, 128, b0r, b0u);
    build_xc0_k<<<dim3(8, 64), 256, 0, stream>>>(inp, H0, RU, XT, t);
    gemm_k<0><<<dim3(8, NC0 / 128, 4), 256, 0, stream>>>(
        Sb, 1024L * 1024, 1024, 32, 0, XT, 1024, 32, AG, 1024L * NC0, NC0, nullptr, nullptr);
    gemm_k<2><<<dim3(500, 1, 1), 256, 0, stream>>>(
        AG, 0, FP0, FP0 / 32, JS0, Wc0, 4 * FP0, 12, H0, 0, 64, b0c, RU);
    // ---- layer 1 ----
    build_xs1_k<<<dim3(8, 64), 256, 0, stream>>>(H0, H1, XT);
    gemm_k<0><<<dim3(8, NC1 / 128, 4), 256, 0, stream>>>(
        Sb, 1024L * 1024, 1024, 32, 0, XT, 1024, 32, AG, 1024L * NC1, NC1, nullptr, nullptr);
    gemm_k<1><<<dim3(500, 1, 1), 256, 0, stream>>>(
        AG, 0, FP1, FP1 / 32, JS1, Wru1, 4 * FP1, 16, RU, 0, 128, b1r, b1u);
    build_xc1_k<<<dim3(8, 64), 256, 0, stream>>>(H0, H1, RU, XT);
    gemm_k<0><<<dim3(8, NC1 / 128, 4), 256, 0, stream>>>(
        Sb, 1024L * 1024, 1024, 32, 0, XT, 1024, 32, AG, 1024L * NC1, NC1, nullptr, nullptr);
    gemm_k<2><<<dim3(500, 1, 1), 256, 0, stream>>>(
        AG, 0, FP1, FP1 / 32, JS1, Wc1, 4 * FP1, 16, H1, 0, 64, b1c, RU);
    // ---- output projection ----
    proj_k<<<250, 256, 0, stream>>>(H1, pw, pb, out, t);
  }
}

// Round 2
// 5210.354 us; speedup vs baseline: 1.1685x; 1.1685x over previous
//
#include <hip/hip_runtime.h>

// DCRNN decoder, restructured (R2):
//  - diffuse-first with reuse: per step diffusion GEMMs are
//      L0ru: S@h0 (N=4096), L0c: S@(r0*h0) (4096), L1ru: S@[h0',h1] (8192),
//      L1c: S@(r1*h1) (4096, reuses S@h0' half) -- 172 GF/step vs 240 before.
//  - S@x_t precomputed for all t in one GEMM (teacher forcing => x known).
//  - diffusion epilogue writes straight into the small-GEMM A layout (cmap).
//  - XCD-aware bijective block swizzle on all GEMMs with nwg%8==0.
// Layouts:
//  H0/H1:  [b][kp(1024)][o(64)] f32        (kp>=1000 rows never read)
//  XT:     [(row)][kp] bf16 rows = B-operand of diffusion (k-contiguous)
//  AG:     [j][m(1024)][K-slot] bf16; L0: slot=b*96+l (l=0:x,1..64:h,65..95:0)
//          L1: slot=b*128+l (0..63:h0', 64..127:h1 or r*h1)
//  RUb:    [(m*64+b)][128] bf16 sigmoid gates (r:0..63, u:64..127)

#define BB 64
#define TT 12
#define NN 1000

typedef __bf16 bf16x8 __attribute__((ext_vector_type(8)));
typedef float f32x4 __attribute__((ext_vector_type(4)));
typedef unsigned short u16x8 __attribute__((ext_vector_type(8)));

__device__ __forceinline__ unsigned short f2b(float f) {
  union { float f; unsigned u; } x; x.f = f;
  unsigned u = x.u;
  u += 0x7FFFu + ((u >> 16) & 1u);
  return (unsigned short)(u >> 16);
}
__device__ __forceinline__ float b2f(unsigned short s) {
  union { float f; unsigned u; } x; x.u = ((unsigned)s) << 16; return x.f;
}

__device__ __forceinline__ void gload16(const void* g, void* l) {
  __builtin_amdgcn_global_load_lds((const __attribute__((address_space(1))) void*)g,
                                   (__attribute__((address_space(3))) void*)l, 16, 0, 0);
}

// ---------------- setup kernels ----------------

__global__ void prep_s_k(const float* __restrict__ S, unsigned short* __restrict__ Sb) {
  long idx = (long)blockIdx.x * 256 + threadIdx.x;   // 4*1024*1024
  if (idx >= 4194304L) return;
  int j = (int)(idx >> 20);
  int r = (int)((idx >> 10) & 1023);
  int c = (int)(idx & 1023);
  float v = (r < NN && c < NN) ? S[((long)j * NN + r) * NN + c] : 0.f;
  Sb[idx] = f2b(v);
}

// WT[o2][j*Fpad + l] = w[j][l][o2'] ; o2<64 from wA, o2>=64 from wB (or 0)
__global__ void prep_wt_k(const float* __restrict__ wA, const float* __restrict__ wB,
                          unsigned short* __restrict__ WT, int F, int Fpad) {
  int Kt = 4 * Fpad;
  int idx = blockIdx.x * 256 + threadIdx.x;
  if (idx >= 128 * Kt) return;
  int o = idx / Kt, kk = idx % Kt;
  int j = kk / Fpad, l = kk % Fpad;
  float v = 0.f;
  if (l < F) {
    if (o < 64) v = wA ? wA[((long)j * F + l) * 64 + o] : 0.f;
    else        v = wB ? wB[((long)j * F + l) * 64 + (o - 64)] : 0.f;
  }
  WT[idx] = f2b(v);
}

// init_hidden [2][B][N][H] -> H[b][kp][o]
__global__ void init_h2_k(const float* __restrict__ ih, float* __restrict__ H0,
                          float* __restrict__ H1) {
  long idx = (long)blockIdx.x * 256 + threadIdx.x;   // 4,096,000
  if (idx >= 4096000L) return;
  int b = (int)(idx / 64000);
  int rem = (int)(idx % 64000);
  int n = rem >> 6, o = rem & 63;
  long dst = ((long)((b << 10) | n)) * 64 + o;
  H0[dst] = ih[idx];
  H1[dst] = ih[4096000L + idx];
}

// all-t x transpose: XT[(t*64+b)][kp], rows 704..767 zero
__global__ void build_xallT_k(const float* __restrict__ inp, unsigned short* __restrict__ XT) {
  unsigned idx = blockIdx.x * 256 + threadIdx.x;     // 768*1024
  if (idx >= 786432u) return;
  int k = idx & 1023, row = idx >> 10;
  int t = row >> 6, b = row & 63;
  float v = (t < TT - 1 && k < NN) ? inp[((long)b * TT + t) * NN + k] : 0.f;
  XT[idx] = f2b(v);
}

// per step: write diffused-x into AG0 slot l=0, zero slots 64..95 (GEMM then
// overwrites 1..64). 262144 threads.
__global__ void scatter_x_k(const unsigned short* __restrict__ XAG,
                            unsigned short* __restrict__ AG, int t) {
  unsigned idx = blockIdx.x * 256 + threadIdx.x;
  if (idx >= 262144u) return;
  int b = idx & 63, m = (idx >> 6) & 1023, j = idx >> 16;
  long base = ((long)((j << 10) | m)) * 6144 + b * 96;
  AG[base] = XAG[((long)((j << 10) | m)) * 768 + t * 64 + b];
  u16x8 z = {0, 0, 0, 0, 0, 0, 0, 0};
  *(u16x8*)(AG + base + 64) = z;
  *(u16x8*)(AG + base + 72) = z;
  *(u16x8*)(AG + base + 80) = z;
  *(u16x8*)(AG + base + 88) = z;
}

// ---------------- transpose builds ----------------
// XT[(b*64+o)][kp] = H[b][k][o] (RMUL: * r from RUb[(k*64+b)*128+o])
template <int RMUL>
__global__ void build_hT_k(const float* __restrict__ H, const unsigned short* __restrict__ RUb,
                           unsigned short* __restrict__ XT) {
  __shared__ float tile[128][65];
  int k0 = blockIdx.x * 128, b = blockIdx.y, tid = threadIdx.x;
  for (int q = 0; q < 32; ++q) {
    int kk = q * 4 + (tid >> 6), o = tid & 63;
    int k = k0 + kk;
    float v = 0.f;
    if (k < NN) {
      v = H[((long)((b << 10) | k)) * 64 + o];
      if (RMUL) v *= b2f(RUb[((long)(k * 64 + b)) * 128 + o]);
    }
    tile[kk][o] = v;
  }
  __syncthreads();
  for (int q = 0; q < 32; ++q) {
    int idx = q * 256 + tid;
    int o = idx >> 7, kk = idx & 127;
    XT[(((long)(b * 64 + o)) << 10) + k0 + kk] = f2b(tile[kk][o]);
  }
}

// XT[(b*128 + l)][kp]: l<64 from H0, l>=64 from H1
__global__ void build_h01T_k(const float* __restrict__ H0, const float* __restrict__ H1,
                             unsigned short* __restrict__ XT) {
  __shared__ float tile[128][65];
  int k0 = blockIdx.x * 128, b = blockIdx.y, tid = threadIdx.x;
  for (int src = 0; src < 2; ++src) {
    const float* H = src ? H1 : H0;
    if (src) __syncthreads();
    for (int q = 0; q < 32; ++q) {
      int kk = q * 4 + (tid >> 6), o = tid & 63;
      int k = k0 + kk;
      tile[kk][o] = (k < NN) ? H[((long)((b << 10) | k)) * 64 + o] : 0.f;
    }
    __syncthreads();
    for (int q = 0; q < 32; ++q) {
      int idx = q * 256 + tid;
      int o = idx >> 7, kk = idx & 127;
      XT[(((long)(b * 128 + src * 64 + o)) << 10) + k0 + kk] = f2b(tile[kk][o]);
    }
  }
}

// ---------------- unified MFMA GEMM ----------------
// C = A[M][K] * BT[*][K]^T ; 128x128 tile, BK=32, 4 waves.
// EPI 3: bf16 store with column remap: C[z*czstr + r*ldc + (c>>6)*cstr+coff+(c&63)]
// EPI 1: RUb[r*128+c] = bf16(sigmoid(acc + bias))   (p0 = b_r, p1v = b_u)
// EPI 4: c<64: H[((r&63)<<10 | r>>6)*64+c] = u*h + (1-u)*tanh(acc+p0[c]),
//        u = RUb[r*128+64+c] (p1v)
template <int EPI>
__global__ __launch_bounds__(256)
void gemm_k(const unsigned short* __restrict__ A, long azstr, int lda, int acs, long ajstr,
            const unsigned short* __restrict__ BT, int ldb, int ksteps,
            void* __restrict__ Cv, long czstr, int ldc, int cstr, int coff,
            const float* __restrict__ p0, const void* __restrict__ p1v) {
  __shared__ unsigned short As[4096];
  __shared__ unsigned short Bs[4096];
  // XCD-aware bijective swizzle (x-minor tile order)
  unsigned nwx = gridDim.x, nwy = gridDim.y;
  unsigned lid = blockIdx.x + nwx * (blockIdx.y + nwy * blockIdx.z);
  unsigned nwg = nwx * nwy * gridDim.z;
  unsigned swz = lid;
  if ((nwg & 7u) == 0) { unsigned cpx = nwg >> 3; swz = (lid & 7u) * cpx + (lid >> 3); }
  unsigned bx = swz % nwx;
  unsigned tmp = swz / nwx;
  unsigned by = tmp % nwy, bz = tmp / nwy;

  const int tid = threadIdx.x;
  const int lane = tid & 63;
  const int w = tid >> 6;
  const int wr = (w >> 1) * 64, wc = (w & 1) * 64;
  const long m0 = (long)bx * 128;
  const long n0 = (long)by * 128;
  A += (long)bz * azstr;

  const int rl = lane & 15;
  const int kb = (lane >> 4) * 8;
  const int s_r = tid >> 2;
  const int s_k = (tid & 3) * 8;

  f32x4 acc[4][4];
  for (int i = 0; i < 4; ++i)
    for (int j = 0; j < 4; ++j)
      acc[i][j] = (f32x4){0.f, 0.f, 0.f, 0.f};

  int jc = 0, lc = 0;
  for (int kt = 0; kt < ksteps; ++kt) {
    const unsigned short* Astep = A + (long)jc * ajstr + (long)lc * 32;
    const unsigned short* Bstep = BT + (long)kt * 32;
    gload16(Astep + (m0 + s_r) * (long)lda + s_k,       &As[tid * 8]);
    gload16(Astep + (m0 + 64 + s_r) * (long)lda + s_k,  &As[2048 + tid * 8]);
    gload16(Bstep + (n0 + s_r) * (long)ldb + s_k,       &Bs[tid * 8]);
    gload16(Bstep + (n0 + 64 + s_r) * (long)ldb + s_k,  &Bs[2048 + tid * 8]);
    __syncthreads();
    bf16x8 af[4], bg[4];
#pragma unroll
    for (int i = 0; i < 4; ++i) {
      af[i] = *(const bf16x8*)((const void*)&As[(wr + i * 16 + rl) * 32 + kb]);
      bg[i] = *(const bf16x8*)((const void*)&Bs[(wc + i * 16 + rl) * 32 + kb]);
    }
#pragma unroll
    for (int mi = 0; mi < 4; ++mi)
#pragma unroll
      for (int ni = 0; ni < 4; ++ni)
        acc[mi][ni] = __builtin_amdgcn_mfma_f32_16x16x32_bf16(af[mi], bg[ni], acc[mi][ni], 0, 0, 0);
    __syncthreads();
    if (++lc == acs) { lc = 0; ++jc; }
  }

  const int rb = (lane >> 4) * 4;      // C/D: row=(lane>>4)*4+reg, col=lane&15
  const int cl = lane & 15;
  if constexpr (EPI == 3) {
    unsigned short* C = (unsigned short*)Cv + (long)bz * czstr;
#pragma unroll
    for (int mi = 0; mi < 4; ++mi) {
      long r = m0 + wr + mi * 16 + rb;
#pragma unroll
      for (int ni = 0; ni < 4; ++ni) {
        int c = (int)(n0 + wc + ni * 16 + cl);
        long cb = (long)(c >> 6) * cstr + coff + (c & 63);
#pragma unroll
        for (int jj = 0; jj < 4; ++jj)
          C[(r + jj) * (long)ldc + cb] = f2b(acc[mi][ni][jj]);
      }
    }
  } else if constexpr (EPI == 1) {
    unsigned short* RUo = (unsigned short*)Cv;
    const float* bu = (const float*)p1v;
#pragma unroll
    for (int mi = 0; mi < 4; ++mi) {
      long r = m0 + wr + mi * 16 + rb;
#pragma unroll
      for (int ni = 0; ni < 4; ++ni) {
        int c = (int)(n0 + wc + ni * 16 + cl);
        float bias = (c < 64) ? p0[c] : bu[c - 64];
#pragma unroll
        for (int jj = 0; jj < 4; ++jj) {
          float v = acc[mi][ni][jj] + bias;
          RUo[(r + jj) * 128 + c] = f2b(1.f / (1.f + __expf(-v)));
        }
      }
    }
  } else {  // EPI == 4
    float* H = (float*)Cv;
    const unsigned short* RUb = (const unsigned short*)p1v;
#pragma unroll
    for (int mi = 0; mi < 4; ++mi) {
      long r = m0 + wr + mi * 16 + rb;
#pragma unroll
      for (int ni = 0; ni < 4; ++ni) {
        int c = (int)(n0 + wc + ni * 16 + cl);
        if (c < 64) {
#pragma unroll
          for (int jj = 0; jj < 4; ++jj) {
            long rr = r + jj;
            float cv = tanhf(acc[mi][ni][jj] + p0[c]);
            float u = b2f(RUb[rr * 128 + 64 + c]);
            long ha = ((((rr & 63)) << 10) + (rr >> 6)) * 64 + c;
            H[ha] = u * H[ha] + (1.f - u) * cv;
          }
        }
      }
    }
  }
}

// ---------------- projection ----------------
__global__ void proj_k(const float* __restrict__ H1, const float* __restrict__ pw,
                       const float* __restrict__ pb, float* __restrict__ out, int t) {
  __shared__ float tile[250][65];
  __shared__ float pws[64];
  int b = blockIdx.y, n0 = blockIdx.x * 250, tid = threadIdx.x;
  if (tid < 64) pws[tid] = pw[tid];
  for (int flat = tid; flat < 16000; flat += 256) {
    int nl = flat >> 6, o = flat & 63;
    tile[nl][o] = H1[((long)((b << 10) | (n0 + nl))) * 64 + o];
  }
  __syncthreads();
  if (tid < 250) {
    float s = pb[0];
#pragma unroll
    for (int o = 0; o < 64; ++o) s += tile[tid][o] * pws[o];
    out[((long)b * (TT - 1) + t) * NN + n0 + tid] = s;
  }
}

// ---------------- launcher ----------------
extern "C" void kernel_launch(void* const* d_in, const int* in_sizes, int n_in,
                              void* d_out, int out_size, void* d_ws, size_t ws_size,
                              hipStream_t stream) {
  const float* inp = (const float*)d_in[0];
  const float* ih  = (const float*)d_in[1];
  const float* sup = (const float*)d_in[2];
  const float* w0r = (const float*)d_in[4];
  const float* b0r = (const float*)d_in[5];
  const float* w0u = (const float*)d_in[6];
  const float* b0u = (const float*)d_in[7];
  const float* w0c = (const float*)d_in[8];
  const float* b0c = (const float*)d_in[9];
  const float* w1r = (const float*)d_in[10];
  const float* b1r = (const float*)d_in[11];
  const float* w1u = (const float*)d_in[12];
  const float* b1u = (const float*)d_in[13];
  const float* w1c = (const float*)d_in[14];
  const float* b1c = (const float*)d_in[15];
  const float* pw  = (const float*)d_in[16];
  const float* pb  = (const float*)d_in[17];
  float* out = (float*)d_out;

  char* ws = (char*)d_ws;
  unsigned short* Sb   = (unsigned short*)(ws + 0);            //  8,388,608
  unsigned short* AG   = (unsigned short*)(ws + 8388608);      // 67,108,864
  unsigned short* XT   = (unsigned short*)(ws + 75497472);     // 16,777,216
  unsigned short* XAG  = (unsigned short*)(ws + 92274688);     //  6,291,456
  unsigned short* RUb  = (unsigned short*)(ws + 98566144);     // 16,384,000
  float* H0            = (float*)(ws + 114950144);             // 16,777,216
  float* H1            = (float*)(ws + 131727360);             // 16,777,216
  unsigned short* Wru0 = (unsigned short*)(ws + 148504576);    //     98,304
  unsigned short* Wc0  = (unsigned short*)(ws + 148602880);    //     98,304
  unsigned short* Wru1 = (unsigned short*)(ws + 148701184);    //    131,072
  unsigned short* Wc1  = (unsigned short*)(ws + 148832256);    //    131,072

  // ---- setup ----
  prep_s_k<<<16384, 256, 0, stream>>>(sup, Sb);
  prep_wt_k<<<192, 256, 0, stream>>>(w0r, w0u, Wru0, 65, 96);
  prep_wt_k<<<192, 256, 0, stream>>>(w0c, nullptr, Wc0, 65, 96);
  prep_wt_k<<<256, 256, 0, stream>>>(w1r, w1u, Wru1, 128, 128);
  prep_wt_k<<<256, 256, 0, stream>>>(w1c, nullptr, Wc1, 128, 128);
  init_h2_k<<<16000, 256, 0, stream>>>(ih, H0, H1);
  build_xallT_k<<<3072, 256, 0, stream>>>(inp, XT);
  // XAG[j][m][(t,b)] = S_j @ x_all
  gemm_k<3><<<dim3(8, 6, 4), 256, 0, stream>>>(
      Sb, 1048576L, 1024, 32, 0, XT, 1024, 32, XAG, 786432L, 768, 64, 0, nullptr, nullptr);

  for (int t = 0; t < TT - 1; ++t) {
    // ---- layer 0 ----
    scatter_x_k<<<1024, 256, 0, stream>>>(XAG, AG, t);
    build_hT_k<0><<<dim3(8, 64), 256, 0, stream>>>(H0, nullptr, XT);
    gemm_k<3><<<dim3(8, 32, 4), 256, 0, stream>>>(
        Sb, 1048576L, 1024, 32, 0, XT, 1024, 32, AG, 6291456L, 6144, 96, 1, nullptr, nullptr);
    gemm_k<1><<<dim3(500, 1, 1), 256, 0, stream>>>(
        AG, 0, 96, 3, 6291456L, Wru0, 384, 12, RUb, 0, 0, 0, 0, b0r, b0u);
    build_hT_k<1><<<dim3(8, 64), 256, 0, stream>>>(H0, RUb, XT);
    gemm_k<3><<<dim3(8, 32, 4), 256, 0, stream>>>(
        Sb, 1048576L, 1024, 32, 0, XT, 1024, 32, AG, 6291456L, 6144, 96, 1, nullptr, nullptr);
    gemm_k<4><<<dim3(500, 1, 1), 256, 0, stream>>>(
        AG, 0, 96, 3, 6291456L, Wc0, 384, 12, H0, 0, 0, 0, 0, b0c, RUb);
    // ---- layer 1 ----
    build_h01T_k<<<dim3(8, 64), 256, 0, stream>>>(H0, H1, XT);
    gemm_k<3><<<dim3(8, 64, 4), 256, 0, stream>>>(
        Sb, 1048576L, 1024, 32, 0, XT, 1024, 32, AG, 8388608L, 8192, 64, 0, nullptr, nullptr);
    gemm_k<1><<<dim3(500, 1, 1), 256, 0, stream>>>(
        AG, 0, 128, 4, 8388608L, Wru1, 512, 16, RUb, 0, 0, 0, 0, b1r, b1u);
    build_hT_k<1><<<dim3(8, 64), 256, 0, stream>>>(H1, RUb, XT);
    gemm_k<3><<<dim3(8, 32, 4), 256, 0, stream>>>(
        Sb, 1048576L, 1024, 32, 0, XT, 1024, 32, AG, 8388608L, 8192, 128, 64, nullptr, nullptr);
    gemm_k<4><<<dim3(500, 1, 1), 256, 0, stream>>>(
        AG, 0, 128, 4, 8388608L, Wc1, 512, 16, H1, 0, 0, 0, 0, b1c, RUb);
    // ---- output projection ----
    proj_k<<<dim3(4, 64), 256, 0, stream>>>(H1, pw, pb, out, t);
  }
}

// Round 6
// 4526.740 us; speedup vs baseline: 1.3450x; 1.1510x over previous
//
#include <hip/hip_runtime.h>

// DCRNN decoder R3 (resubmit #3 after infra timeouts): diffusion GEMMs on
// 256x256 / BK=64 / 8-wave / 8-phase pipelined kernel (T2 swizzle + T3/T4
// counted vmcnt + T5 setprio). Small per-node GEMMs (K=384/512) stay on the
// 128^2 kernel.
// Layouts:
//  H0/H1:  [b][kp(1024)][o(64)] f32
//  XT:     [row][kp] bf16 (B-operand, K-contiguous)
//  AG:     [j][m(1024)][slot] bf16; L0 slot=b*96+l; L1 slot=b*128+l
//  RUb:    [(m*64+b)][128] bf16 gates

#define BB 64
#define TT 12
#define NN 1000

typedef __bf16 bf16x8 __attribute__((ext_vector_type(8)));
typedef float f32x4 __attribute__((ext_vector_type(4)));
typedef unsigned short u16x8 __attribute__((ext_vector_type(8)));

__device__ __forceinline__ unsigned short f2b(float f) {
  union { float f; unsigned u; } x; x.f = f;
  unsigned u = x.u;
  u += 0x7FFFu + ((u >> 16) & 1u);
  return (unsigned short)(u >> 16);
}
__device__ __forceinline__ float b2f(unsigned short s) {
  union { float f; unsigned u; } x; x.u = ((unsigned)s) << 16; return x.f;
}

__device__ __forceinline__ void gload16(const void* g, void* l) {
  __builtin_amdgcn_global_load_lds((const __attribute__((address_space(1))) void*)g,
                                   (__attribute__((address_space(3))) void*)l, 16, 0, 0);
}

#define FENCE asm volatile("" ::: "memory")
#define BAR { FENCE; __builtin_amdgcn_s_barrier(); FENCE; }
#define VMCNT(n) asm volatile("s_waitcnt vmcnt(" #n ")" ::: "memory")

// ---------------- setup kernels ----------------

__global__ void prep_s_k(const float* __restrict__ S, unsigned short* __restrict__ Sb) {
  long idx = (long)blockIdx.x * 256 + threadIdx.x;   // 4*1024*1024
  if (idx >= 4194304L) return;
  int j = (int)(idx >> 20);
  int r = (int)((idx >> 10) & 1023);
  int c = (int)(idx & 1023);
  float v = (r < NN && c < NN) ? S[((long)j * NN + r) * NN + c] : 0.f;
  Sb[idx] = f2b(v);
}

__global__ void prep_wt_k(const float* __restrict__ wA, const float* __restrict__ wB,
                          unsigned short* __restrict__ WT, int F, int Fpad) {
  int Kt = 4 * Fpad;
  int idx = blockIdx.x * 256 + threadIdx.x;
  if (idx >= 128 * Kt) return;
  int o = idx / Kt, kk = idx % Kt;
  int j = kk / Fpad, l = kk % Fpad;
  float v = 0.f;
  if (l < F) {
    if (o < 64) v = wA ? wA[((long)j * F + l) * 64 + o] : 0.f;
    else        v = wB ? wB[((long)j * F + l) * 64 + (o - 64)] : 0.f;
  }
  WT[idx] = f2b(v);
}

__global__ void init_h2_k(const float* __restrict__ ih, float* __restrict__ H0,
                          float* __restrict__ H1) {
  long idx = (long)blockIdx.x * 256 + threadIdx.x;   // 4,096,000
  if (idx >= 4096000L) return;
  int b = (int)(idx / 64000);
  int rem = (int)(idx % 64000);
  int n = rem >> 6, o = rem & 63;
  long dst = ((long)((b << 10) | n)) * 64 + o;
  H0[dst] = ih[idx];
  H1[dst] = ih[4096000L + idx];
}

__global__ void build_xallT_k(const float* __restrict__ inp, unsigned short* __restrict__ XT) {
  unsigned idx = blockIdx.x * 256 + threadIdx.x;     // 768*1024
  if (idx >= 786432u) return;
  int k = idx & 1023, row = idx >> 10;
  int t = row >> 6, b = row & 63;
  float v = (t < TT - 1 && k < NN) ? inp[((long)b * TT + t) * NN + k] : 0.f;
  XT[idx] = f2b(v);
}

__global__ void scatter_x_k(const unsigned short* __restrict__ XAG,
                            unsigned short* __restrict__ AG, int t) {
  unsigned idx = blockIdx.x * 256 + threadIdx.x;
  if (idx >= 262144u) return;
  int b = idx & 63, m = (idx >> 6) & 1023, j = idx >> 16;
  long base = ((long)((j << 10) | m)) * 6144 + b * 96;
  AG[base] = XAG[((long)((j << 10) | m)) * 768 + t * 64 + b];
  u16x8 z = {0, 0, 0, 0, 0, 0, 0, 0};
  *(u16x8*)(AG + base + 64) = z;
  *(u16x8*)(AG + base + 72) = z;
  *(u16x8*)(AG + base + 80) = z;
  *(u16x8*)(AG + base + 88) = z;
}

// ---------------- transpose builds ----------------
template <int RMUL>
__global__ void build_hT_k(const float* __restrict__ H, const unsigned short* __restrict__ RUb,
                           unsigned short* __restrict__ XT) {
  __shared__ float tile[128][65];
  int k0 = blockIdx.x * 128, b = blockIdx.y, tid = threadIdx.x;
  for (int q = 0; q < 32; ++q) {
    int kk = q * 4 + (tid >> 6), o = tid & 63;
    int k = k0 + kk;
    float v = 0.f;
    if (k < NN) {
      v = H[((long)((b << 10) | k)) * 64 + o];
      if (RMUL) v *= b2f(RUb[((long)(k * 64 + b)) * 128 + o]);
    }
    tile[kk][o] = v;
  }
  __syncthreads();
  for (int q = 0; q < 32; ++q) {
    int idx = q * 256 + tid;
    int o = idx >> 7, kk = idx & 127;
    XT[(((long)(b * 64 + o)) << 10) + k0 + kk] = f2b(tile[kk][o]);
  }
}

__global__ void build_h01T_k(const float* __restrict__ H0, const float* __restrict__ H1,
                             unsigned short* __restrict__ XT) {
  __shared__ float tile[128][65];
  int k0 = blockIdx.x * 128, b = blockIdx.y, tid = threadIdx.x;
  for (int src = 0; src < 2; ++src) {
    const float* H = src ? H1 : H0;
    if (src) __syncthreads();
    for (int q = 0; q < 32; ++q) {
      int kk = q * 4 + (tid >> 6), o = tid & 63;
      int k = k0 + kk;
      tile[kk][o] = (k < NN) ? H[((long)((b << 10) | k)) * 64 + o] : 0.f;
    }
    __syncthreads();
    for (int q = 0; q < 32; ++q) {
      int idx = q * 256 + tid;
      int o = idx >> 7, kk = idx & 127;
      XT[(((long)(b * 128 + src * 64 + o)) << 10) + k0 + kk] = f2b(tile[kk][o]);
    }
  }
}

// ---------------- 256^2 8-phase diffusion GEMM ----------------
// C = A[1024][1024] (z-batched) * BT[*][1024]^T, all K=1024. BM=BN=256, BK=64,
// 8 waves (2Mx4N), 2 K-tiles per iteration, LDS 128KB (2 dbuf x (A 32K + B 32K)).
// Swizzle: byte ^= (row&7)<<4 on both gload-source and ds_read.

__device__ __forceinline__ void stageA256(const char* Ag, char* L, int s, int tid) {
  int w = tid >> 6, l = tid & 63;
#pragma unroll
  for (int q = 0; q < 2; ++q) {
    int row = s * 128 + (q * 8 + w) * 8 + (l >> 3);
    int cb = ((l & 7) * 16) ^ ((row & 7) << 4);
    gload16(Ag + (long)row * 2048 + cb, L + row * 128 + (l & 7) * 16);
  }
}
__device__ __forceinline__ void stageB256(const char* Bg, char* L, int st, int tid) {
  int w = tid >> 6, l = tid & 63;
#pragma unroll
  for (int q = 0; q < 2; ++q) {
    int rr = (q * 8 + w) * 8 + (l >> 3);
    int row = ((rr >> 5) << 6) + st * 32 + (rr & 31);
    int cb = ((l & 7) * 16) ^ ((row & 7) << 4);
    gload16(Bg + (long)row * 2048 + cb, L + row * 128 + (l & 7) * 16);
  }
}

__device__ __forceinline__ void rdA(const char* L, bf16x8 (&af)[4][2], int rowbase, int l) {
  int lr = l & 15, g = (l >> 4) * 16;
#pragma unroll
  for (int mi = 0; mi < 4; ++mi) {
    int row = rowbase + mi * 16 + lr;
#pragma unroll
    for (int ks = 0; ks < 2; ++ks)
      af[mi][ks] = *(const bf16x8*)(L + row * 128 + ((ks * 64 + g) ^ ((row & 7) << 4)));
  }
}
template <int NI0>
__device__ __forceinline__ void rdB(const char* L, bf16x8 (&bf)[4][2], int rowbase, int l) {
  int lr = l & 15, g = (l >> 4) * 16;
#pragma unroll
  for (int ni = 0; ni < 2; ++ni) {
    int row = rowbase + (NI0 + ni) * 16 + lr;
#pragma unroll
    for (int ks = 0; ks < 2; ++ks)
      bf[NI0 + ni][ks] = *(const bf16x8*)(L + row * 128 + ((ks * 64 + g) ^ ((row & 7) << 4)));
  }
}
template <int QM, int QN>
__device__ __forceinline__ void mfmaQ(f32x4 (&acc)[8][4], bf16x8 (&af)[4][2],
                                      bf16x8 (&bf)[4][2]) {
  __builtin_amdgcn_s_setprio(1);
#pragma unroll
  for (int mi = 0; mi < 4; ++mi)
#pragma unroll
    for (int ni = 0; ni < 2; ++ni)
#pragma unroll
      for (int ks = 0; ks < 2; ++ks)
        acc[QM * 4 + mi][QN * 2 + ni] = __builtin_amdgcn_mfma_f32_16x16x32_bf16(
            af[mi][ks], bf[QN * 2 + ni][ks], acc[QM * 4 + mi][QN * 2 + ni], 0, 0, 0);
  __builtin_amdgcn_s_setprio(0);
}

__global__ __launch_bounds__(512, 2)
void gemm256_k(const unsigned short* __restrict__ A, long azstr,
               const unsigned short* __restrict__ BT,
               void* __restrict__ Cv, long czstr, int ldc, int cstr, int coff) {
  alignas(16) __shared__ char lds[131072];
  char* A0 = lds;
  char* B0 = lds + 32768;
  char* A1 = lds + 65536;
  char* B1 = lds + 98304;

  // XCD-aware bijective swizzle (all grids have nwg % 8 == 0)
  unsigned nwx = gridDim.x, nwy = gridDim.y;
  unsigned lid = blockIdx.x + nwx * (blockIdx.y + nwy * blockIdx.z);
  unsigned cpx = (nwx * nwy * gridDim.z) >> 3;
  unsigned swz = (lid & 7u) * cpx + (lid >> 3);
  unsigned bx = swz % nwx;
  unsigned tmp = swz / nwx;
  unsigned by = tmp % nwy, bz = tmp / nwy;

  const int tid = threadIdx.x;
  const int l = tid & 63;
  const int w = tid >> 6;
  const int wrb = (w >> 2) * 128;    // wave M-block
  const int wcb = (w & 3) * 64;      // wave N-block
  const long m0 = (long)bx * 256;
  const long n0 = (long)by * 256;

  const char* Ag = (const char*)A + (long)bz * azstr * 2 + m0 * 2048;
  const char* Bg = (const char*)BT + n0 * 2048;

  f32x4 acc[8][4];
#pragma unroll
  for (int i = 0; i < 8; ++i)
#pragma unroll
    for (int j = 0; j < 4; ++j)
      acc[i][j] = (f32x4){0.f, 0.f, 0.f, 0.f};
  bf16x8 af[4][2], bf[4][2];

  // prologue: buf0 <- kt 0 (all 4 regions), buf1 <- kt 1 (3 of 4 regions)
  stageB256(Bg, B0, 0, tid);
  stageB256(Bg, B0, 1, tid);
  stageA256(Ag, A0, 0, tid);
  stageA256(Ag, A0, 1, tid);
  stageB256(Bg + 128, B1, 0, tid);
  stageB256(Bg + 128, B1, 1, tid);
  stageA256(Ag + 128, A1, 0, tid);
  VMCNT(6);
  BAR;

  for (int it = 0; it < 8; ++it) {
    const bool L7 = (it == 7);
    const int k0b = it * 256;        // kt0 byte offset; +128 kt1; +256 kt0+2; +384 kt1+2
    // P0: compute buf0 q(0,0); stage buf1.AH1 <- kt1
    VMCNT(6);
    rdA(A0, af, wrb, l);
    rdB<0>(B0, bf, wcb, l);
    stageA256(Ag + k0b + 128, A1, 1, tid);
    BAR; mfmaQ<0, 0>(acc, af, bf); BAR;
    // P1: stage buf0.BS0 <- kt0+2
    rdB<2>(B0, bf, wcb, l);
    if (!L7) stageB256(Bg + k0b + 256, B0, 0, tid);
    BAR; mfmaQ<0, 1>(acc, af, bf); BAR;
    // P2: stage buf0.BS1
    rdA(A0, af, wrb + 64, l);
    if (!L7) stageB256(Bg + k0b + 256, B0, 1, tid);
    BAR; mfmaQ<1, 0>(acc, af, bf); BAR;
    // P3: stage buf0.AH0
    if (!L7) stageA256(Ag + k0b + 256, A0, 0, tid);
    BAR; mfmaQ<1, 1>(acc, af, bf); BAR;
    // P4: compute buf1 q(0,0); stage buf0.AH1
    if (L7) { VMCNT(0); } else { VMCNT(6); }
    rdA(A1, af, wrb, l);
    rdB<0>(B1, bf, wcb, l);
    if (!L7) stageA256(Ag + k0b + 256, A0, 1, tid);
    BAR; mfmaQ<0, 0>(acc, af, bf); BAR;
    // P5: stage buf1.BS0 <- kt1+2
    rdB<2>(B1, bf, wcb, l);
    if (!L7) stageB256(Bg + k0b + 384, B1, 0, tid);
    BAR; mfmaQ<0, 1>(acc, af, bf); BAR;
    // P6: stage buf1.BS1
    rdA(A1, af, wrb + 64, l);
    if (!L7) stageB256(Bg + k0b + 384, B1, 1, tid);
    BAR; mfmaQ<1, 0>(acc, af, bf); BAR;
    // P7: stage buf1.AH0
    if (!L7) stageA256(Ag + k0b + 384, A1, 0, tid);
    BAR; mfmaQ<1, 1>(acc, af, bf); BAR;
  }

  // epilogue: bf16 store with column remap
  unsigned short* C = (unsigned short*)Cv + (long)bz * czstr;
  const int rb = (l >> 4) * 4, cl = l & 15;
#pragma unroll
  for (int mi = 0; mi < 8; ++mi) {
    long r = m0 + wrb + mi * 16 + rb;
#pragma unroll
    for (int ni = 0; ni < 4; ++ni) {
      int c = (int)(n0 + wcb + ni * 16 + cl);
      long cb = (long)(c >> 6) * cstr + coff + (c & 63);
#pragma unroll
      for (int jj = 0; jj < 4; ++jj)
        C[(r + jj) * (long)ldc + cb] = f2b(acc[mi][ni][jj]);
    }
  }
}

// ---------------- small MFMA GEMM (K=384/512) ----------------
// EPI 1: RUb[r*128+c] = bf16(sigmoid(acc + bias)) (p0 = b_r, p1v = b_u)
// EPI 4: c<64: H[((r&63)<<10 | r>>6)*64+c] = u*h + (1-u)*tanh(acc+p0[c])
template <int EPI>
__global__ __launch_bounds__(256)
void gemm_k(const unsigned short* __restrict__ A, long azstr, int lda, int acs, long ajstr,
            const unsigned short* __restrict__ BT, int ldb, int ksteps,
            void* __restrict__ Cv, long czstr, int ldc, int cstr, int coff,
            const float* __restrict__ p0, const void* __restrict__ p1v) {
  __shared__ unsigned short As[4096];
  __shared__ unsigned short Bs[4096];
  unsigned bx = blockIdx.x, by = blockIdx.y, bz = blockIdx.z;

  const int tid = threadIdx.x;
  const int lane = tid & 63;
  const int w = tid >> 6;
  const int wr = (w >> 1) * 64, wc = (w & 1) * 64;
  const long m0 = (long)bx * 128;
  const long n0 = (long)by * 128;
  A += (long)bz * azstr;

  const int rl = lane & 15;
  const int kb = (lane >> 4) * 8;
  const int s_r = tid >> 2;
  const int s_k = (tid & 3) * 8;

  f32x4 acc[4][4];
  for (int i = 0; i < 4; ++i)
    for (int j = 0; j < 4; ++j)
      acc[i][j] = (f32x4){0.f, 0.f, 0.f, 0.f};

  int jc = 0, lc = 0;
  for (int kt = 0; kt < ksteps; ++kt) {
    const unsigned short* Astep = A + (long)jc * ajstr + (long)lc * 32;
    const unsigned short* Bstep = BT + (long)kt * 32;
    gload16(Astep + (m0 + s_r) * (long)lda + s_k,       &As[tid * 8]);
    gload16(Astep + (m0 + 64 + s_r) * (long)lda + s_k,  &As[2048 + tid * 8]);
    gload16(Bstep + (n0 + s_r) * (long)ldb + s_k,       &Bs[tid * 8]);
    gload16(Bstep + (n0 + 64 + s_r) * (long)ldb + s_k,  &Bs[2048 + tid * 8]);
    __syncthreads();
    bf16x8 af[4], bg[4];
#pragma unroll
    for (int i = 0; i < 4; ++i) {
      af[i] = *(const bf16x8*)((const void*)&As[(wr + i * 16 + rl) * 32 + kb]);
      bg[i] = *(const bf16x8*)((const void*)&Bs[(wc + i * 16 + rl) * 32 + kb]);
    }
#pragma unroll
    for (int mi = 0; mi < 4; ++mi)
#pragma unroll
      for (int ni = 0; ni < 4; ++ni)
        acc[mi][ni] = __builtin_amdgcn_mfma_f32_16x16x32_bf16(af[mi], bg[ni], acc[mi][ni], 0, 0, 0);
    __syncthreads();
    if (++lc == acs) { lc = 0; ++jc; }
  }

  const int rb = (lane >> 4) * 4;
  const int cl = lane & 15;
  if constexpr (EPI == 1) {
    unsigned short* RUo = (unsigned short*)Cv;
    const float* bu = (const float*)p1v;
#pragma unroll
    for (int mi = 0; mi < 4; ++mi) {
      long r = m0 + wr + mi * 16 + rb;
#pragma unroll
      for (int ni = 0; ni < 4; ++ni) {
        int c = (int)(n0 + wc + ni * 16 + cl);
        float bias = (c < 64) ? p0[c] : bu[c - 64];
#pragma unroll
        for (int jj = 0; jj < 4; ++jj) {
          float v = acc[mi][ni][jj] + bias;
          RUo[(r + jj) * 128 + c] = f2b(1.f / (1.f + __expf(-v)));
        }
      }
    }
  } else {  // EPI == 4
    float* H = (float*)Cv;
    const unsigned short* RUb = (const unsigned short*)p1v;
#pragma unroll
    for (int mi = 0; mi < 4; ++mi) {
      long r = m0 + wr + mi * 16 + rb;
#pragma unroll
      for (int ni = 0; ni < 4; ++ni) {
        int c = (int)(n0 + wc + ni * 16 + cl);
        if (c < 64) {
#pragma unroll
          for (int jj = 0; jj < 4; ++jj) {
            long rr = r + jj;
            float cv = tanhf(acc[mi][ni][jj] + p0[c]);
            float u = b2f(RUb[rr * 128 + 64 + c]);
            long ha = ((((rr & 63)) << 10) + (rr >> 6)) * 64 + c;
            H[ha] = u * H[ha] + (1.f - u) * cv;
          }
        }
      }
    }
  }
}

// ---------------- projection ----------------
__global__ void proj_k(const float* __restrict__ H1, const float* __restrict__ pw,
                       const float* __restrict__ pb, float* __restrict__ out, int t) {
  __shared__ float tile[250][65];
  __shared__ float pws[64];
  int b = blockIdx.y, n0 = blockIdx.x * 250, tid = threadIdx.x;
  if (tid < 64) pws[tid] = pw[tid];
  for (int flat = tid; flat < 16000; flat += 256) {
    int nl = flat >> 6, o = flat & 63;
    tile[nl][o] = H1[((long)((b << 10) | (n0 + nl))) * 64 + o];
  }
  __syncthreads();
  if (tid < 250) {
    float s = pb[0];
#pragma unroll
    for (int o = 0; o < 64; ++o) s += tile[tid][o] * pws[o];
    out[((long)b * (TT - 1) + t) * NN + n0 + tid] = s;
  }
}

// ---------------- launcher ----------------
extern "C" void kernel_launch(void* const* d_in, const int* in_sizes, int n_in,
                              void* d_out, int out_size, void* d_ws, size_t ws_size,
                              hipStream_t stream) {
  const float* inp = (const float*)d_in[0];
  const float* ih  = (const float*)d_in[1];
  const float* sup = (const float*)d_in[2];
  const float* w0r = (const float*)d_in[4];
  const float* b0r = (const float*)d_in[5];
  const float* w0u = (const float*)d_in[6];
  const float* b0u = (const float*)d_in[7];
  const float* w0c = (const float*)d_in[8];
  const float* b0c = (const float*)d_in[9];
  const float* w1r = (const float*)d_in[10];
  const float* b1r = (const float*)d_in[11];
  const float* w1u = (const float*)d_in[12];
  const float* b1u = (const float*)d_in[13];
  const float* w1c = (const float*)d_in[14];
  const float* b1c = (const float*)d_in[15];
  const float* pw  = (const float*)d_in[16];
  const float* pb  = (const float*)d_in[17];
  float* out = (float*)d_out;

  char* ws = (char*)d_ws;
  unsigned short* Sb   = (unsigned short*)(ws + 0);            //  8,388,608
  unsigned short* AG   = (unsigned short*)(ws + 8388608);      // 67,108,864
  unsigned short* XT   = (unsigned short*)(ws + 75497472);     // 16,777,216
  unsigned short* XAG  = (unsigned short*)(ws + 92274688);     //  6,291,456
  unsigned short* RUb  = (unsigned short*)(ws + 98566144);     // 16,384,000
  float* H0            = (float*)(ws + 114950144);             // 16,777,216
  float* H1            = (float*)(ws + 131727360);             // 16,777,216
  unsigned short* Wru0 = (unsigned short*)(ws + 148504576);    //     98,304
  unsigned short* Wc0  = (unsigned short*)(ws + 148602880);    //     98,304
  unsigned short* Wru1 = (unsigned short*)(ws + 148701184);    //    131,072
  unsigned short* Wc1  = (unsigned short*)(ws + 148832256);    //    131,072

  // ---- setup ----
  prep_s_k<<<16384, 256, 0, stream>>>(sup, Sb);
  prep_wt_k<<<192, 256, 0, stream>>>(w0r, w0u, Wru0, 65, 96);
  prep_wt_k<<<192, 256, 0, stream>>>(w0c, nullptr, Wc0, 65, 96);
  prep_wt_k<<<256, 256, 0, stream>>>(w1r, w1u, Wru1, 128, 128);
  prep_wt_k<<<256, 256, 0, stream>>>(w1c, nullptr, Wc1, 128, 128);
  init_h2_k<<<16000, 256, 0, stream>>>(ih, H0, H1);
  build_xallT_k<<<3072, 256, 0, stream>>>(inp, XT);
  // XAG[j][m][(t,b)] = S_j @ x_all
  gemm256_k<<<dim3(4, 3, 4), 512, 0, stream>>>(Sb, 1048576L, XT, XAG, 786432L, 768, 64, 0);

  for (int t = 0; t < TT - 1; ++t) {
    // ---- layer 0 ----
    scatter_x_k<<<1024, 256, 0, stream>>>(XAG, AG, t);
    build_hT_k<0><<<dim3(8, 64), 256, 0, stream>>>(H0, nullptr, XT);
    gemm256_k<<<dim3(4, 16, 4), 512, 0, stream>>>(Sb, 1048576L, XT, AG, 6291456L, 6144, 96, 1);
    gemm_k<1><<<dim3(500, 1, 1), 256, 0, stream>>>(
        AG, 0, 96, 3, 6291456L, Wru0, 384, 12, RUb, 0, 0, 0, 0, b0r, b0u);
    build_hT_k<1><<<dim3(8, 64), 256, 0, stream>>>(H0, RUb, XT);
    gemm256_k<<<dim3(4, 16, 4), 512, 0, stream>>>(Sb, 1048576L, XT, AG, 6291456L, 6144, 96, 1);
    gemm_k<4><<<dim3(500, 1, 1), 256, 0, stream>>>(
        AG, 0, 96, 3, 6291456L, Wc0, 384, 12, H0, 0, 0, 0, 0, b0c, RUb);
    // ---- layer 1 ----
    build_h01T_k<<<dim3(8, 64), 256, 0, stream>>>(H0, H1, XT);
    gemm256_k<<<dim3(4, 32, 4), 512, 0, stream>>>(Sb, 1048576L, XT, AG, 8388608L, 8192, 64, 0);
    gemm_k<1><<<dim3(500, 1, 1), 256, 0, stream>>>(
        AG, 0, 128, 4, 8388608L, Wru1, 512, 16, RUb, 0, 0, 0, 0, b1r, b1u);
    build_hT_k<1><<<dim3(8, 64), 256, 0, stream>>>(H1, RUb, XT);
    gemm256_k<<<dim3(4, 16, 4), 512, 0, stream>>>(Sb, 1048576L, XT, AG, 8388608L, 8192, 128, 64);
    gemm_k<4><<<dim3(500, 1, 1), 256, 0, stream>>>(
        AG, 0, 128, 4, 8388608L, Wc1, 512, 16, H1, 0, 0, 0, 0, b1c, RUb);
    // ---- output projection ----
    proj_k<<<dim3(4, 64), 256, 0, stream>>>(H1, pw, pb, out, t);
  }
}

// Round 8
// 4509.636 us; speedup vs baseline: 1.3501x; 1.0038x over previous
//
#include <hip/hip_runtime.h>

// DCRNN decoder R7 (resubmit after infra timeout): R3 + two changes in
// gemm256_k only:
//  (1) mfmaQ loop order ks->mi->ni (indep distance 8, was dependent pairs)
//  (2) explicit lgkmcnt(0) + sched_barrier(0) before each MFMA burst
// Layouts:
//  H0/H1:  [b][kp(1024)][o(64)] f32
//  XT:     [row][kp] bf16 (B-operand, K-contiguous)
//  AG:     [j][m(1024)][slot] bf16; L0 slot=b*96+l; L1 slot=b*128+l
//  RUb:    [(m*64+b)][128] bf16 gates

#define BB 64
#define TT 12
#define NN 1000

typedef __bf16 bf16x8 __attribute__((ext_vector_type(8)));
typedef float f32x4 __attribute__((ext_vector_type(4)));
typedef unsigned short u16x8 __attribute__((ext_vector_type(8)));

__device__ __forceinline__ unsigned short f2b(float f) {
  union { float f; unsigned u; } x; x.f = f;
  unsigned u = x.u;
  u += 0x7FFFu + ((u >> 16) & 1u);
  return (unsigned short)(u >> 16);
}
__device__ __forceinline__ float b2f(unsigned short s) {
  union { float f; unsigned u; } x; x.u = ((unsigned)s) << 16; return x.f;
}

__device__ __forceinline__ void gload16(const void* g, void* l) {
  __builtin_amdgcn_global_load_lds((const __attribute__((address_space(1))) void*)g,
                                   (__attribute__((address_space(3))) void*)l, 16, 0, 0);
}

#define FENCE asm volatile("" ::: "memory")
#define BAR { FENCE; __builtin_amdgcn_s_barrier(); FENCE; }
#define VMCNT(n) asm volatile("s_waitcnt vmcnt(" #n ")" ::: "memory")

// ---------------- setup kernels ----------------

__global__ void prep_s_k(const float* __restrict__ S, unsigned short* __restrict__ Sb) {
  long idx = (long)blockIdx.x * 256 + threadIdx.x;   // 4*1024*1024
  if (idx >= 4194304L) return;
  int j = (int)(idx >> 20);
  int r = (int)((idx >> 10) & 1023);
  int c = (int)(idx & 1023);
  float v = (r < NN && c < NN) ? S[((long)j * NN + r) * NN + c] : 0.f;
  Sb[idx] = f2b(v);
}

__global__ void prep_wt_k(const float* __restrict__ wA, const float* __restrict__ wB,
                          unsigned short* __restrict__ WT, int F, int Fpad) {
  int Kt = 4 * Fpad;
  int idx = blockIdx.x * 256 + threadIdx.x;
  if (idx >= 128 * Kt) return;
  int o = idx / Kt, kk = idx % Kt;
  int j = kk / Fpad, l = kk % Fpad;
  float v = 0.f;
  if (l < F) {
    if (o < 64) v = wA ? wA[((long)j * F + l) * 64 + o] : 0.f;
    else        v = wB ? wB[((long)j * F + l) * 64 + (o - 64)] : 0.f;
  }
  WT[idx] = f2b(v);
}

__global__ void init_h2_k(const float* __restrict__ ih, float* __restrict__ H0,
                          float* __restrict__ H1) {
  long idx = (long)blockIdx.x * 256 + threadIdx.x;   // 4,096,000
  if (idx >= 4096000L) return;
  int b = (int)(idx / 64000);
  int rem = (int)(idx % 64000);
  int n = rem >> 6, o = rem & 63;
  long dst = ((long)((b << 10) | n)) * 64 + o;
  H0[dst] = ih[idx];
  H1[dst] = ih[4096000L + idx];
}

__global__ void build_xallT_k(const float* __restrict__ inp, unsigned short* __restrict__ XT) {
  unsigned idx = blockIdx.x * 256 + threadIdx.x;     // 768*1024
  if (idx >= 786432u) return;
  int k = idx & 1023, row = idx >> 10;
  int t = row >> 6, b = row & 63;
  float v = (t < TT - 1 && k < NN) ? inp[((long)b * TT + t) * NN + k] : 0.f;
  XT[idx] = f2b(v);
}

__global__ void scatter_x_k(const unsigned short* __restrict__ XAG,
                            unsigned short* __restrict__ AG, int t) {
  unsigned idx = blockIdx.x * 256 + threadIdx.x;
  if (idx >= 262144u) return;
  int b = idx & 63, m = (idx >> 6) & 1023, j = idx >> 16;
  long base = ((long)((j << 10) | m)) * 6144 + b * 96;
  AG[base] = XAG[((long)((j << 10) | m)) * 768 + t * 64 + b];
  u16x8 z = {0, 0, 0, 0, 0, 0, 0, 0};
  *(u16x8*)(AG + base + 64) = z;
  *(u16x8*)(AG + base + 72) = z;
  *(u16x8*)(AG + base + 80) = z;
  *(u16x8*)(AG + base + 88) = z;
}

// ---------------- transpose builds ----------------
template <int RMUL>
__global__ void build_hT_k(const float* __restrict__ H, const unsigned short* __restrict__ RUb,
                           unsigned short* __restrict__ XT) {
  __shared__ float tile[128][65];
  int k0 = blockIdx.x * 128, b = blockIdx.y, tid = threadIdx.x;
  for (int q = 0; q < 32; ++q) {
    int kk = q * 4 + (tid >> 6), o = tid & 63;
    int k = k0 + kk;
    float v = 0.f;
    if (k < NN) {
      v = H[((long)((b << 10) | k)) * 64 + o];
      if (RMUL) v *= b2f(RUb[((long)(k * 64 + b)) * 128 + o]);
    }
    tile[kk][o] = v;
  }
  __syncthreads();
  for (int q = 0; q < 32; ++q) {
    int idx = q * 256 + tid;
    int o = idx >> 7, kk = idx & 127;
    XT[(((long)(b * 64 + o)) << 10) + k0 + kk] = f2b(tile[kk][o]);
  }
}

__global__ void build_h01T_k(const float* __restrict__ H0, const float* __restrict__ H1,
                             unsigned short* __restrict__ XT) {
  __shared__ float tile[128][65];
  int k0 = blockIdx.x * 128, b = blockIdx.y, tid = threadIdx.x;
  for (int src = 0; src < 2; ++src) {
    const float* H = src ? H1 : H0;
    if (src) __syncthreads();
    for (int q = 0; q < 32; ++q) {
      int kk = q * 4 + (tid >> 6), o = tid & 63;
      int k = k0 + kk;
      tile[kk][o] = (k < NN) ? H[((long)((b << 10) | k)) * 64 + o] : 0.f;
    }
    __syncthreads();
    for (int q = 0; q < 32; ++q) {
      int idx = q * 256 + tid;
      int o = idx >> 7, kk = idx & 127;
      XT[(((long)(b * 128 + src * 64 + o)) << 10) + k0 + kk] = f2b(tile[kk][o]);
    }
  }
}

// ---------------- 256^2 8-phase diffusion GEMM ----------------
// C = A[1024][1024] (z-batched) * BT[*][1024]^T, all K=1024. BM=BN=256, BK=64,
// 8 waves (2Mx4N), 2 K-tiles per iteration, LDS 128KB (2 dbuf x (A 32K + B 32K)).
// Swizzle: byte ^= (row&7)<<4 on both gload-source and ds_read.

__device__ __forceinline__ void stageA256(const char* Ag, char* L, int s, int tid) {
  int w = tid >> 6, l = tid & 63;
#pragma unroll
  for (int q = 0; q < 2; ++q) {
    int row = s * 128 + (q * 8 + w) * 8 + (l >> 3);
    int cb = ((l & 7) * 16) ^ ((row & 7) << 4);
    gload16(Ag + (long)row * 2048 + cb, L + row * 128 + (l & 7) * 16);
  }
}
__device__ __forceinline__ void stageB256(const char* Bg, char* L, int st, int tid) {
  int w = tid >> 6, l = tid & 63;
#pragma unroll
  for (int q = 0; q < 2; ++q) {
    int rr = (q * 8 + w) * 8 + (l >> 3);
    int row = ((rr >> 5) << 6) + st * 32 + (rr & 31);
    int cb = ((l & 7) * 16) ^ ((row & 7) << 4);
    gload16(Bg + (long)row * 2048 + cb, L + row * 128 + (l & 7) * 16);
  }
}

__device__ __forceinline__ void rdA(const char* L, bf16x8 (&af)[4][2], int rowbase, int l) {
  int lr = l & 15, g = (l >> 4) * 16;
#pragma unroll
  for (int mi = 0; mi < 4; ++mi) {
    int row = rowbase + mi * 16 + lr;
#pragma unroll
    for (int ks = 0; ks < 2; ++ks)
      af[mi][ks] = *(const bf16x8*)(L + row * 128 + ((ks * 64 + g) ^ ((row & 7) << 4)));
  }
}
template <int NI0>
__device__ __forceinline__ void rdB(const char* L, bf16x8 (&bf)[4][2], int rowbase, int l) {
  int lr = l & 15, g = (l >> 4) * 16;
#pragma unroll
  for (int ni = 0; ni < 2; ++ni) {
    int row = rowbase + (NI0 + ni) * 16 + lr;
#pragma unroll
    for (int ks = 0; ks < 2; ++ks)
      bf[NI0 + ni][ks] = *(const bf16x8*)(L + row * 128 + ((ks * 64 + g) ^ ((row & 7) << 4)));
  }
}
// ks OUTER: 8 independent MFMAs per ks-slice; acc element still accumulates
// ks0 then ks1 (numerics identical to ks-inner).
template <int QM, int QN>
__device__ __forceinline__ void mfmaQ(f32x4 (&acc)[8][4], bf16x8 (&af)[4][2],
                                      bf16x8 (&bf)[4][2]) {
  asm volatile("s_waitcnt lgkmcnt(0)" ::: "memory");
  __builtin_amdgcn_sched_barrier(0);
  __builtin_amdgcn_s_setprio(1);
#pragma unroll
  for (int ks = 0; ks < 2; ++ks)
#pragma unroll
    for (int mi = 0; mi < 4; ++mi)
#pragma unroll
      for (int ni = 0; ni < 2; ++ni)
        acc[QM * 4 + mi][QN * 2 + ni] = __builtin_amdgcn_mfma_f32_16x16x32_bf16(
            af[mi][ks], bf[QN * 2 + ni][ks], acc[QM * 4 + mi][QN * 2 + ni], 0, 0, 0);
  __builtin_amdgcn_s_setprio(0);
}

__global__ __launch_bounds__(512, 2)
void gemm256_k(const unsigned short* __restrict__ A, long azstr,
               const unsigned short* __restrict__ BT,
               void* __restrict__ Cv, long czstr, int ldc, int cstr, int coff) {
  alignas(16) __shared__ char lds[131072];
  char* A0 = lds;
  char* B0 = lds + 32768;
  char* A1 = lds + 65536;
  char* B1 = lds + 98304;

  // XCD-aware bijective swizzle (all grids have nwg % 8 == 0)
  unsigned nwx = gridDim.x, nwy = gridDim.y;
  unsigned lid = blockIdx.x + nwx * (blockIdx.y + nwy * blockIdx.z);
  unsigned cpx = (nwx * nwy * gridDim.z) >> 3;
  unsigned swz = (lid & 7u) * cpx + (lid >> 3);
  unsigned bx = swz % nwx;
  unsigned tmp = swz / nwx;
  unsigned by = tmp % nwy, bz = tmp / nwy;

  const int tid = threadIdx.x;
  const int l = tid & 63;
  const int w = tid >> 6;
  const int wrb = (w >> 2) * 128;    // wave M-block
  const int wcb = (w & 3) * 64;      // wave N-block
  const long m0 = (long)bx * 256;
  const long n0 = (long)by * 256;

  const char* Ag = (const char*)A + (long)bz * azstr * 2 + m0 * 2048;
  const char* Bg = (const char*)BT + n0 * 2048;

  f32x4 acc[8][4];
#pragma unroll
  for (int i = 0; i < 8; ++i)
#pragma unroll
    for (int j = 0; j < 4; ++j)
      acc[i][j] = (f32x4){0.f, 0.f, 0.f, 0.f};
  bf16x8 af[4][2], bf[4][2];

  // prologue: buf0 <- kt 0 (all 4 regions), buf1 <- kt 1 (3 of 4 regions)
  stageB256(Bg, B0, 0, tid);
  stageB256(Bg, B0, 1, tid);
  stageA256(Ag, A0, 0, tid);
  stageA256(Ag, A0, 1, tid);
  stageB256(Bg + 128, B1, 0, tid);
  stageB256(Bg + 128, B1, 1, tid);
  stageA256(Ag + 128, A1, 0, tid);
  VMCNT(6);
  BAR;

  for (int it = 0; it < 8; ++it) {
    const bool L7 = (it == 7);
    const int k0b = it * 256;        // kt0 byte offset; +128 kt1; +256 kt0+2; +384 kt1+2
    // P0: compute buf0 q(0,0); stage buf1.AH1 <- kt1
    VMCNT(6);
    rdA(A0, af, wrb, l);
    rdB<0>(B0, bf, wcb, l);
    stageA256(Ag + k0b + 128, A1, 1, tid);
    BAR; mfmaQ<0, 0>(acc, af, bf); BAR;
    // P1: stage buf0.BS0 <- kt0+2
    rdB<2>(B0, bf, wcb, l);
    if (!L7) stageB256(Bg + k0b + 256, B0, 0, tid);
    BAR; mfmaQ<0, 1>(acc, af, bf); BAR;
    // P2: stage buf0.BS1
    rdA(A0, af, wrb + 64, l);
    if (!L7) stageB256(Bg + k0b + 256, B0, 1, tid);
    BAR; mfmaQ<1, 0>(acc, af, bf); BAR;
    // P3: stage buf0.AH0
    if (!L7) stageA256(Ag + k0b + 256, A0, 0, tid);
    BAR; mfmaQ<1, 1>(acc, af, bf); BAR;
    // P4: compute buf1 q(0,0); stage buf0.AH1
    if (L7) { VMCNT(0); } else { VMCNT(6); }
    rdA(A1, af, wrb, l);
    rdB<0>(B1, bf, wcb, l);
    if (!L7) stageA256(Ag + k0b + 256, A0, 1, tid);
    BAR; mfmaQ<0, 0>(acc, af, bf); BAR;
    // P5: stage buf1.BS0 <- kt1+2
    rdB<2>(B1, bf, wcb, l);
    if (!L7) stageB256(Bg + k0b + 384, B1, 0, tid);
    BAR; mfmaQ<0, 1>(acc, af, bf); BAR;
    // P6: stage buf1.BS1
    rdA(A1, af, wrb + 64, l);
    if (!L7) stageB256(Bg + k0b + 384, B1, 1, tid);
    BAR; mfmaQ<1, 0>(acc, af, bf); BAR;
    // P7: stage buf1.AH0
    if (!L7) stageA256(Ag + k0b + 384, A1, 0, tid);
    BAR; mfmaQ<1, 1>(acc, af, bf); BAR;
  }

  // epilogue: bf16 store with column remap
  unsigned short* C = (unsigned short*)Cv + (long)bz * czstr;
  const int rb = (l >> 4) * 4, cl = l & 15;
#pragma unroll
  for (int mi = 0; mi < 8; ++mi) {
    long r = m0 + wrb + mi * 16 + rb;
#pragma unroll
    for (int ni = 0; ni < 4; ++ni) {
      int c = (int)(n0 + wcb + ni * 16 + cl);
      long cb = (long)(c >> 6) * cstr + coff + (c & 63);
#pragma unroll
      for (int jj = 0; jj < 4; ++jj)
        C[(r + jj) * (long)ldc + cb] = f2b(acc[mi][ni][jj]);
    }
  }
}

// ---------------- small MFMA GEMM (K=384/512) ----------------
// EPI 1: RUb[r*128+c] = bf16(sigmoid(acc + bias)) (p0 = b_r, p1v = b_u)
// EPI 4: c<64: H[((r&63)<<10 | r>>6)*64+c] = u*h + (1-u)*tanh(acc+p0[c])
template <int EPI>
__global__ __launch_bounds__(256)
void gemm_k(const unsigned short* __restrict__ A, long azstr, int lda, int acs, long ajstr,
            const unsigned short* __restrict__ BT, int ldb, int ksteps,
            void* __restrict__ Cv, long czstr, int ldc, int cstr, int coff,
            const float* __restrict__ p0, const void* __restrict__ p1v) {
  __shared__ unsigned short As[4096];
  __shared__ unsigned short Bs[4096];
  unsigned bx = blockIdx.x, by = blockIdx.y, bz = blockIdx.z;

  const int tid = threadIdx.x;
  const int lane = tid & 63;
  const int w = tid >> 6;
  const int wr = (w >> 1) * 64, wc = (w & 1) * 64;
  const long m0 = (long)bx * 128;
  const long n0 = (long)by * 128;
  A += (long)bz * azstr;

  const int rl = lane & 15;
  const int kb = (lane >> 4) * 8;
  const int s_r = tid >> 2;
  const int s_k = (tid & 3) * 8;

  f32x4 acc[4][4];
  for (int i = 0; i < 4; ++i)
    for (int j = 0; j < 4; ++j)
      acc[i][j] = (f32x4){0.f, 0.f, 0.f, 0.f};

  int jc = 0, lc = 0;
  for (int kt = 0; kt < ksteps; ++kt) {
    const unsigned short* Astep = A + (long)jc * ajstr + (long)lc * 32;
    const unsigned short* Bstep = BT + (long)kt * 32;
    gload16(Astep + (m0 + s_r) * (long)lda + s_k,       &As[tid * 8]);
    gload16(Astep + (m0 + 64 + s_r) * (long)lda + s_k,  &As[2048 + tid * 8]);
    gload16(Bstep + (n0 + s_r) * (long)ldb + s_k,       &Bs[tid * 8]);
    gload16(Bstep + (n0 + 64 + s_r) * (long)ldb + s_k,  &Bs[2048 + tid * 8]);
    __syncthreads();
    bf16x8 af[4], bg[4];
#pragma unroll
    for (int i = 0; i < 4; ++i) {
      af[i] = *(const bf16x8*)((const void*)&As[(wr + i * 16 + rl) * 32 + kb]);
      bg[i] = *(const bf16x8*)((const void*)&Bs[(wc + i * 16 + rl) * 32 + kb]);
    }
#pragma unroll
    for (int mi = 0; mi < 4; ++mi)
#pragma unroll
      for (int ni = 0; ni < 4; ++ni)
        acc[mi][ni] = __builtin_amdgcn_mfma_f32_16x16x32_bf16(af[mi], bg[ni], acc[mi][ni], 0, 0, 0);
    __syncthreads();
    if (++lc == acs) { lc = 0; ++jc; }
  }

  const int rb = (lane >> 4) * 4;
  const int cl = lane & 15;
  if constexpr (EPI == 1) {
    unsigned short* RUo = (unsigned short*)Cv;
    const float* bu = (const float*)p1v;
#pragma unroll
    for (int mi = 0; mi < 4; ++mi) {
      long r = m0 + wr + mi * 16 + rb;
#pragma unroll
      for (int ni = 0; ni < 4; ++ni) {
        int c = (int)(n0 + wc + ni * 16 + cl);
        float bias = (c < 64) ? p0[c] : bu[c - 64];
#pragma unroll
        for (int jj = 0; jj < 4; ++jj) {
          float v = acc[mi][ni][jj] + bias;
          RUo[(r + jj) * 128 + c] = f2b(1.f / (1.f + __expf(-v)));
        }
      }
    }
  } else {  // EPI == 4
    float* H = (float*)Cv;
    const unsigned short* RUb = (const unsigned short*)p1v;
#pragma unroll
    for (int mi = 0; mi < 4; ++mi) {
      long r = m0 + wr + mi * 16 + rb;
#pragma unroll
      for (int ni = 0; ni < 4; ++ni) {
        int c = (int)(n0 + wc + ni * 16 + cl);
        if (c < 64) {
#pragma unroll
          for (int jj = 0; jj < 4; ++jj) {
            long rr = r + jj;
            float cv = tanhf(acc[mi][ni][jj] + p0[c]);
            float u = b2f(RUb[rr * 128 + 64 + c]);
            long ha = ((((rr & 63)) << 10) + (rr >> 6)) * 64 + c;
            H[ha] = u * H[ha] + (1.f - u) * cv;
          }
        }
      }
    }
  }
}

// ---------------- projection ----------------
__global__ void proj_k(const float* __restrict__ H1, const float* __restrict__ pw,
                       const float* __restrict__ pb, float* __restrict__ out, int t) {
  __shared__ float tile[250][65];
  __shared__ float pws[64];
  int b = blockIdx.y, n0 = blockIdx.x * 250, tid = threadIdx.x;
  if (tid < 64) pws[tid] = pw[tid];
  for (int flat = tid; flat < 16000; flat += 256) {
    int nl = flat >> 6, o = flat & 63;
    tile[nl][o] = H1[((long)((b << 10) | (n0 + nl))) * 64 + o];
  }
  __syncthreads();
  if (tid < 250) {
    float s = pb[0];
#pragma unroll
    for (int o = 0; o < 64; ++o) s += tile[tid][o] * pws[o];
    out[((long)b * (TT - 1) + t) * NN + n0 + tid] = s;
  }
}

// ---------------- launcher ----------------
extern "C" void kernel_launch(void* const* d_in, const int* in_sizes, int n_in,
                              void* d_out, int out_size, void* d_ws, size_t ws_size,
                              hipStream_t stream) {
  const float* inp = (const float*)d_in[0];
  const float* ih  = (const float*)d_in[1];
  const float* sup = (const float*)d_in[2];
  const float* w0r = (const float*)d_in[4];
  const float* b0r = (const float*)d_in[5];
  const float* w0u = (const float*)d_in[6];
  const float* b0u = (const float*)d_in[7];
  const float* w0c = (const float*)d_in[8];
  const float* b0c = (const float*)d_in[9];
  const float* w1r = (const float*)d_in[10];
  const float* b1r = (const float*)d_in[11];
  const float* w1u = (const float*)d_in[12];
  const float* b1u = (const float*)d_in[13];
  const float* w1c = (const float*)d_in[14];
  const float* b1c = (const float*)d_in[15];
  const float* pw  = (const float*)d_in[16];
  const float* pb  = (const float*)d_in[17];
  float* out = (float*)d_out;

  char* ws = (char*)d_ws;
  unsigned short* Sb   = (unsigned short*)(ws + 0);            //  8,388,608
  unsigned short* AG   = (unsigned short*)(ws + 8388608);      // 67,108,864
  unsigned short* XT   = (unsigned short*)(ws + 75497472);     // 16,777,216
  unsigned short* XAG  = (unsigned short*)(ws + 92274688);     //  6,291,456
  unsigned short* RUb  = (unsigned short*)(ws + 98566144);     // 16,384,000
  float* H0            = (float*)(ws + 114950144);             // 16,777,216
  float* H1            = (float*)(ws + 131727360);             // 16,777,216
  unsigned short* Wru0 = (unsigned short*)(ws + 148504576);    //     98,304
  unsigned short* Wc0  = (unsigned short*)(ws + 148602880);    //     98,304
  unsigned short* Wru1 = (unsigned short*)(ws + 148701184);    //    131,072
  unsigned short* Wc1  = (unsigned short*)(ws + 148832256);    //    131,072

  // ---- setup ----
  prep_s_k<<<16384, 256, 0, stream>>>(sup, Sb);
  prep_wt_k<<<192, 256, 0, stream>>>(w0r, w0u, Wru0, 65, 96);
  prep_wt_k<<<192, 256, 0, stream>>>(w0c, nullptr, Wc0, 65, 96);
  prep_wt_k<<<256, 256, 0, stream>>>(w1r, w1u, Wru1, 128, 128);
  prep_wt_k<<<256, 256, 0, stream>>>(w1c, nullptr, Wc1, 128, 128);
  init_h2_k<<<16000, 256, 0, stream>>>(ih, H0, H1);
  build_xallT_k<<<3072, 256, 0, stream>>>(inp, XT);
  // XAG[j][m][(t,b)] = S_j @ x_all
  gemm256_k<<<dim3(4, 3, 4), 512, 0, stream>>>(Sb, 1048576L, XT, XAG, 786432L, 768, 64, 0);

  for (int t = 0; t < TT - 1; ++t) {
    // ---- layer 0 ----
    scatter_x_k<<<1024, 256, 0, stream>>>(XAG, AG, t);
    build_hT_k<0><<<dim3(8, 64), 256, 0, stream>>>(H0, nullptr, XT);
    gemm256_k<<<dim3(4, 16, 4), 512, 0, stream>>>(Sb, 1048576L, XT, AG, 6291456L, 6144, 96, 1);
    gemm_k<1><<<dim3(500, 1, 1), 256, 0, stream>>>(
        AG, 0, 96, 3, 6291456L, Wru0, 384, 12, RUb, 0, 0, 0, 0, b0r, b0u);
    build_hT_k<1><<<dim3(8, 64), 256, 0, stream>>>(H0, RUb, XT);
    gemm256_k<<<dim3(4, 16, 4), 512, 0, stream>>>(Sb, 1048576L, XT, AG, 6291456L, 6144, 96, 1);
    gemm_k<4><<<dim3(500, 1, 1), 256, 0, stream>>>(
        AG, 0, 96, 3, 6291456L, Wc0, 384, 12, H0, 0, 0, 0, 0, b0c, RUb);
    // ---- layer 1 ----
    build_h01T_k<<<dim3(8, 64), 256, 0, stream>>>(H0, H1, XT);
    gemm256_k<<<dim3(4, 32, 4), 512, 0, stream>>>(Sb, 1048576L, XT, AG, 8388608L, 8192, 64, 0);
    gemm_k<1><<<dim3(500, 1, 1), 256, 0, stream>>>(
        AG, 0, 128, 4, 8388608L, Wru1, 512, 16, RUb, 0, 0, 0, 0, b1r, b1u);
    build_hT_k<1><<<dim3(8, 64), 256, 0, stream>>>(H1, RUb, XT);
    gemm256_k<<<dim3(4, 16, 4), 512, 0, stream>>>(Sb, 1048576L, XT, AG, 8388608L, 8192, 128, 64);
    gemm_k<4><<<dim3(500, 1, 1), 256, 0, stream>>>(
        AG, 0, 128, 4, 8388608L, Wc1, 512, 16, H1, 0, 0, 0, 0, b1c, RUb);
    // ---- output projection ----
    proj_k<<<dim3(4, 64), 256, 0, stream>>>(H1, pw, pb, out, t);
  }
}